// Round 4
// baseline (130.151 us; speedup 1.0000x reference)
//
#include <hip/hip_runtime.h>
#include <hip/hip_bf16.h>
#include <math.h>

#define SS 2048
#define HH 16
#define DD 128
#define HD (HH*DD)
#define QBLK 64
#define KVBLK 64

typedef __attribute__((ext_vector_type(8))) short bf16x8;
typedef __attribute__((ext_vector_type(4))) float f32x4;

#define EXP2(x) exp2f(x)

__device__ __forceinline__ ushort f2bf(float f) {
  __hip_bfloat16 h = __float2bfloat16(f);
  return __builtin_bit_cast(ushort, h);
}

// ---------------------------------------------------------------------------
// Prep: K fp32 [t][h][d] -> bf16 Kbf [h][t][d];  V fp32 -> bf16 VTg [h][d][t]
// ---------------------------------------------------------------------------
__global__ __launch_bounds__(256, 4)
void prep_kv(const float* __restrict__ K, const float* __restrict__ V,
             ushort* __restrict__ Kbf, ushort* __restrict__ VTg) {
  __shared__ ushort Vlds[64][136];
  const int tid = threadIdx.x;
  const int h  = blockIdx.x & 15;
  const int t0 = (blockIdx.x >> 4) * 64;

  // K: streaming convert, coalesced in and out
  #pragma unroll
  for (int j = 0; j < 2; ++j) {
    int li = tid + j * 256;
    int t  = li >> 3;
    int c  = (li & 7) << 4;
    const float* src = K + ((size_t)(t0 + t) * HH + h) * DD + c;
    ushort tmp[16];
    #pragma unroll
    for (int q = 0; q < 4; ++q) {
      float4 x = *(const float4*)(src + 4 * q);
      tmp[4*q+0] = f2bf(x.x); tmp[4*q+1] = f2bf(x.y);
      tmp[4*q+2] = f2bf(x.z); tmp[4*q+3] = f2bf(x.w);
    }
    ushort* dst = Kbf + ((size_t)h * SS + t0 + t) * DD + c;
    *(uint4*)dst       = *(uint4*)&tmp[0];
    *(uint4*)(dst + 8) = *(uint4*)&tmp[8];
  }

  // V: load+convert into LDS tile [t][d]
  #pragma unroll
  for (int j = 0; j < 2; ++j) {
    int li = tid + j * 256;
    int t  = li >> 3;
    int c  = (li & 7) << 4;
    const float* src = V + ((size_t)(t0 + t) * HH + h) * DD + c;
    #pragma unroll
    for (int q = 0; q < 4; ++q) {
      float4 x = *(const float4*)(src + 4 * q);
      ushort4 w; w.x = f2bf(x.x); w.y = f2bf(x.y); w.z = f2bf(x.z); w.w = f2bf(x.w);
      *(ushort4*)&Vlds[t][c + 4 * q] = w;
    }
  }
  __syncthreads();

  // transpose out: VT[h][d][t0..t0+63]
  #pragma unroll
  for (int j = 0; j < 2; ++j) {
    int li  = tid + j * 256;
    int d   = li >> 2;
    int t16 = (li & 3) << 4;
    ushort tmp[16];
    #pragma unroll
    for (int k = 0; k < 16; ++k) tmp[k] = Vlds[t16 + k][d];
    ushort* dst = VTg + ((size_t)h * DD + d) * SS + t0 + t16;
    *(uint4*)dst       = *(uint4*)&tmp[0];
    *(uint4*)(dst + 8) = *(uint4*)&tmp[8];
  }
}

// ---------------------------------------------------------------------------
// Flash attention, bf16 K/V from workspace, XOR-swizzled LDS tiles
// ---------------------------------------------------------------------------
__global__ __launch_bounds__(256, 3)
void attn_fwd(const float* __restrict__ Q, const ushort* __restrict__ Kbf,
              const ushort* __restrict__ VTg, float* __restrict__ O) {
  __shared__ alignas(16) ushort Klds[KVBLK * DD];    // 16 KB, byte ^= (row&7)<<4, row=byte>>8
  __shared__ alignas(16) ushort VTlds[DD * KVBLK];   // 16 KB, byte ^= (row&7)<<4, row=byte>>7
  __shared__ alignas(16) ushort Plds[4][16][72];     // 9.2 KB

  const int tid  = threadIdx.x;
  const int lane = tid & 63;
  const int wid  = tid >> 6;
  const int n    = lane & 15;
  const int g    = lane >> 4;
  const int kx   = (n & 7) << 4;     // read-side XOR (row&7 == n&7 for row = k*16+n)

  const int h  = blockIdx.x & (HH - 1);
  const int j  = blockIdx.x >> 4;
  const int qt = (j < 16) ? (31 - j) : (j - 16);   // pair long+short per CU
  const int qb = qt * QBLK;
  const int qw = qb + 16 * wid;

  const float SCALE = 1.44269504088896f / sqrtf((float)DD);

  // ---- preload Q fragments (A operand), scaled, bf16 ----
  bf16x8 qfrag[4];
  {
    const float* qrow = Q + ((size_t)(qw + n) * HH + h) * DD;
    #pragma unroll
    for (int ks = 0; ks < 4; ++ks) {
      const int d0 = 32 * ks + 8 * g;
      float4 x = *(const float4*)&qrow[d0];
      float4 y = *(const float4*)&qrow[d0 + 4];
      bf16x8 a;
      a[0] = (short)f2bf(x.x * SCALE); a[1] = (short)f2bf(x.y * SCALE);
      a[2] = (short)f2bf(x.z * SCALE); a[3] = (short)f2bf(x.w * SCALE);
      a[4] = (short)f2bf(y.x * SCALE); a[5] = (short)f2bf(y.y * SCALE);
      a[6] = (short)f2bf(y.z * SCALE); a[7] = (short)f2bf(y.w * SCALE);
      qfrag[ks] = a;
    }
  }

  f32x4 acc[8];
  #pragma unroll
  for (int d0 = 0; d0 < 8; ++d0) { acc[d0][0]=0.f; acc[d0][1]=0.f; acc[d0][2]=0.f; acc[d0][3]=0.f; }
  float m[4] = { -INFINITY, -INFINITY, -INFINITY, -INFINITY };
  float l[4] = { 0.f, 0.f, 0.f, 0.f };

  const ushort* Kh  = Kbf + (size_t)h * SS * DD;
  const ushort* VTh = VTg + (size_t)h * DD * SS;
  const int nt = qb / KVBLK + 1;

  uint4 kreg[4], vreg[4];

  // prefetch tile 0
  #pragma unroll
  for (int it = 0; it < 4; ++it) {
    int e = (tid + it * 256) * 8;          // ushort index within 16KB tile
    kreg[it] = *(const uint4*)(Kh + e);    // t0 = 0
    int d = e >> 6, c = e & 63;
    vreg[it] = *(const uint4*)(VTh + (size_t)d * SS + c);
  }

  for (int itile = 0; itile < nt; ++itile) {
    __syncthreads();   // previous tile's LDS fully consumed

    // ---- regs -> LDS (swizzled) ----
    #pragma unroll
    for (int it = 0; it < 4; ++it) {
      int e  = (tid + it * 256) * 8;
      int by = 2 * e;
      *(uint4*)((char*)Klds  + (by ^ (((e >> 7) & 7) << 4))) = kreg[it];
      *(uint4*)((char*)VTlds + (by ^ (((e >> 6) & 7) << 4))) = vreg[it];
    }
    __syncthreads();   // tile ready

    // ---- prefetch next tile ----
    if (itile + 1 < nt) {
      const int t0n = (itile + 1) * KVBLK;
      #pragma unroll
      for (int it = 0; it < 4; ++it) {
        int e = (tid + it * 256) * 8;
        kreg[it] = *(const uint4*)(Kh + (size_t)t0n * DD + e);
        int d = e >> 6, c = e & 63;
        vreg[it] = *(const uint4*)(VTh + (size_t)d * SS + t0n + c);
      }
    }

    const int t0 = itile * KVBLK;

    // ---- QK^T: S[q][t], 16x64 per wave ----
    f32x4 s[4];
    #pragma unroll
    for (int sub = 0; sub < 4; ++sub) { s[sub][0]=0.f; s[sub][1]=0.f; s[sub][2]=0.f; s[sub][3]=0.f; }
    #pragma unroll
    for (int ks = 0; ks < 4; ++ks) {
      #pragma unroll
      for (int sub = 0; sub < 4; ++sub) {
        bf16x8 b = *(const bf16x8*)((const char*)Klds +
                     (sub * 16 + n) * 256 + ((64 * ks + 16 * g) ^ kx));
        s[sub] = __builtin_amdgcn_mfma_f32_16x16x32_bf16(qfrag[ks], b, s[sub], 0, 0, 0);
      }
    }

    // ---- causal mask (diagonal tiles only) ----
    if (t0 + KVBLK - 1 > qw) {
      #pragma unroll
      for (int sub = 0; sub < 4; ++sub) {
        int tg = t0 + sub * 16 + n;
        #pragma unroll
        for (int r = 0; r < 4; ++r) {
          int qg = qw + 4 * g + r;
          if (tg > qg) s[sub][r] = -INFINITY;
        }
      }
    }

    // ---- online softmax (log2 domain) ----
    float mr[4];
    #pragma unroll
    for (int r = 0; r < 4; ++r)
      mr[r] = fmaxf(fmaxf(s[0][r], s[1][r]), fmaxf(s[2][r], s[3][r]));
    #pragma unroll
    for (int off = 1; off <= 8; off <<= 1) {
      #pragma unroll
      for (int r = 0; r < 4; ++r)
        mr[r] = fmaxf(mr[r], __shfl_xor(mr[r], off));
    }
    float corr[4];
    #pragma unroll
    for (int r = 0; r < 4; ++r) {
      float mn = fmaxf(m[r], mr[r]);
      corr[r] = EXP2(m[r] - mn);
      m[r] = mn;
    }
    float sr[4] = { 0.f, 0.f, 0.f, 0.f };
    #pragma unroll
    for (int sub = 0; sub < 4; ++sub) {
      #pragma unroll
      for (int r = 0; r < 4; ++r) {
        float p = EXP2(s[sub][r] - m[r]);
        sr[r] += p;
        Plds[wid][4 * g + r][sub * 16 + n] = f2bf(p);
      }
    }
    #pragma unroll
    for (int off = 1; off <= 8; off <<= 1) {
      #pragma unroll
      for (int r = 0; r < 4; ++r)
        sr[r] += __shfl_xor(sr[r], off);
    }
    #pragma unroll
    for (int r = 0; r < 4; ++r) l[r] = l[r] * corr[r] + sr[r];
    #pragma unroll
    for (int d0 = 0; d0 < 8; ++d0) {
      #pragma unroll
      for (int r = 0; r < 4; ++r) acc[d0][r] *= corr[r];
    }

    // ---- PV: O += P * V ----
    #pragma unroll
    for (int ks = 0; ks < 2; ++ks) {
      bf16x8 a = *(const bf16x8*)&Plds[wid][n][32 * ks + 8 * g];
      #pragma unroll
      for (int d0 = 0; d0 < 8; ++d0) {
        bf16x8 b = *(const bf16x8*)((const char*)VTlds +
                     (d0 * 16 + n) * 128 + ((64 * ks + 16 * g) ^ kx));
        acc[d0] = __builtin_amdgcn_mfma_f32_16x16x32_bf16(a, b, acc[d0], 0, 0, 0);
      }
    }
  }

  // ---- epilogue: normalize and store fp32 ----
  float invl[4];
  #pragma unroll
  for (int r = 0; r < 4; ++r) invl[r] = 1.0f / l[r];
  #pragma unroll
  for (int d0 = 0; d0 < 8; ++d0) {
    #pragma unroll
    for (int r = 0; r < 4; ++r) {
      O[((size_t)(qw + 4 * g + r) * HH + h) * DD + d0 * 16 + n] = acc[d0][r] * invl[r];
    }
  }
}

extern "C" void kernel_launch(void* const* d_in, const int* in_sizes, int n_in,
                              void* d_out, int out_size, void* d_ws, size_t ws_size,
                              hipStream_t stream) {
  const float* Q = (const float*)d_in[0];
  const float* K = (const float*)d_in[1];
  const float* V = (const float*)d_in[2];
  float* O = (float*)d_out;

  const size_t kv_elems = (size_t)HH * SS * DD;   // 4,194,304 ushorts each
  ushort* Kbf = (ushort*)d_ws;
  ushort* VTg = Kbf + kv_elems;                   // total 16.8 MB (ws >= 42 MB proven)

  prep_kv<<<dim3(HH * (SS / 64)), 256, 0, stream>>>(K, V, Kbf, VTg);
  attn_fwd<<<dim3((SS / QBLK) * HH), 256, 0, stream>>>(Q, Kbf, VTg, O);
}